// Round 4
// baseline (522.877 us; speedup 1.0000x reference)
//
#include <hip/hip_runtime.h>
#include <hip/hip_bf16.h>
#include <cstdint>

typedef unsigned short u16;
typedef __attribute__((ext_vector_type(8))) short bf16x8;
typedef __attribute__((ext_vector_type(4))) float f32x4;

#define BATCH 4
#define CDIM 256
#define NTOK 4096   // H*W

__device__ inline float fexp2(float x) { return __builtin_amdgcn_exp2f(x); }

__device__ inline u16 f2bf(float f) {
  union { float f; uint32_t u; } un; un.f = f;
  uint32_t u = un.u;
  u += 0x7fffu + ((u >> 16) & 1u);
  return (u16)(u >> 16);
}
__device__ inline float bf2f(u16 h) {
  union { uint32_t u; float f; } un; un.u = ((uint32_t)h) << 16; return un.f;
}

// Anti-rematerialization pin: zero-instruction asm that "redefines" the value,
// so LLVM cannot re-issue the originating load under register pressure
// (R2/R3 post-mortem: remat collapsed the pipeline -> VGPR 96, 363us).
__device__ inline void pinv(bf16x8& v) { asm volatile("" : "+v"(v)); }

// ---------------------------------------------------------------------------
// LayerNorm: x [B, C, N] -> xn bf16 [B*N, C]
// ---------------------------------------------------------------------------
__global__ __launch_bounds__(256) void ln_kernel(const float* __restrict__ x,
                                                 const float* __restrict__ gamma,
                                                 const float* __restrict__ beta,
                                                 u16* __restrict__ xn) {
  __shared__ float tile[CDIM][33];
  __shared__ float reds[8][32];
  __shared__ float reds2[8][32];
  __shared__ float mu_s[32], rs_s[32];

  int b  = blockIdx.x >> 7;
  int n0 = (blockIdx.x & 127) * 32;
  const float* xb = x + (size_t)b * CDIM * NTOK;

  int t = threadIdx.x & 31;
  int g = threadIdx.x >> 5;

  for (int c = g; c < CDIM; c += 8)
    tile[c][t] = xb[(size_t)c * NTOK + n0 + t];
  __syncthreads();

  float s = 0.f, s2 = 0.f;
  for (int c = g * 32; c < g * 32 + 32; ++c) {
    float v = tile[c][t];
    s += v; s2 += v * v;
  }
  reds[g][t] = s; reds2[g][t] = s2;
  __syncthreads();
  if (threadIdx.x < 32) {
    float ts = 0.f, ts2 = 0.f;
    for (int gg = 0; gg < 8; ++gg) { ts += reds[gg][threadIdx.x]; ts2 += reds2[gg][threadIdx.x]; }
    float mu = ts / CDIM;
    float var = ts2 / CDIM - mu * mu;
    mu_s[threadIdx.x] = mu;
    rs_s[threadIdx.x] = rsqrtf(var + 1e-5f);
  }
  __syncthreads();

  int c = threadIdx.x;
  float gam = gamma[c], bet = beta[c];
  u16* out = xn + ((size_t)b * NTOK + n0) * CDIM;
  for (int tt = 0; tt < 32; ++tt) {
    float v = tile[c][tt];
    float y = (v - mu_s[tt]) * rs_s[tt] * gam + bet;
    out[(size_t)tt * CDIM + c] = f2bf(y);
  }
}

// ---------------------------------------------------------------------------
// W [K, Cout] fp32 -> WT bf16 [Cout, K], optional scale (log2e for Wq)
// ---------------------------------------------------------------------------
__global__ __launch_bounds__(256) void wt_kernel(const float* __restrict__ W,
                                                 u16* __restrict__ WT,
                                                 float scale) {
  __shared__ float tile[32][33];
  int i0 = blockIdx.y * 32;
  int j0 = blockIdx.x * 32;
  int tx = threadIdx.x, ty = threadIdx.y;
  for (int r = ty; r < 32; r += 8)
    tile[r][tx] = W[(size_t)(i0 + r) * CDIM + j0 + tx];
  __syncthreads();
  for (int r = ty; r < 32; r += 8)
    WT[(size_t)(j0 + r) * CDIM + i0 + tx] = f2bf(tile[tx][r] * scale);
}

// ---------------------------------------------------------------------------
// Fused QKV projection (unchanged)
// ---------------------------------------------------------------------------
__global__ __launch_bounds__(256) void qkv_kernel(const u16* __restrict__ A,
                                                  const u16* __restrict__ B3,
                                                  u16* __restrict__ Qb,
                                                  u16* __restrict__ Kb,
                                                  u16* __restrict__ VT) {
  constexpr int BM = 128, BN = 64, BK = 32;
  __shared__ u16 shA[BM][BK + 8];
  __shared__ u16 shB[BN][BK + 8];

  int m0 = blockIdx.y * BM;
  int n0 = blockIdx.x * BN;

  int tid  = threadIdx.x;
  int lane = tid & 63;
  int wave = tid >> 6;
  int wm = wave >> 1, wn = wave & 1;
  int col  = lane & 15;
  int quad = lane >> 4;

  f32x4 acc[4][2];
#pragma unroll
  for (int i = 0; i < 4; ++i)
#pragma unroll
    for (int j = 0; j < 2; ++j) acc[i][j] = (f32x4){0.f, 0.f, 0.f, 0.f};

  for (int kb = 0; kb < CDIM; kb += BK) {
    __syncthreads();
#pragma unroll
    for (int c = tid; c < BM * BK / 8; c += 256) {
      int row = c >> 2, kc = c & 3;
      *(uint4*)&shA[row][kc * 8] = *(const uint4*)&A[(size_t)(m0 + row) * CDIM + kb + kc * 8];
    }
#pragma unroll
    for (int c = tid; c < BN * BK / 8; c += 256) {
      int row = c >> 2, kc = c & 3;
      *(uint4*)&shB[row][kc * 8] = *(const uint4*)&B3[(size_t)(n0 + row) * CDIM + kb + kc * 8];
    }
    __syncthreads();

    bf16x8 af[4], bfv[2];
#pragma unroll
    for (int i = 0; i < 4; ++i)
      af[i] = *(const bf16x8*)&shA[wm * 64 + i * 16 + col][quad * 8];
#pragma unroll
    for (int j = 0; j < 2; ++j)
      bfv[j] = *(const bf16x8*)&shB[wn * 32 + j * 16 + col][quad * 8];
#pragma unroll
    for (int i = 0; i < 4; ++i)
#pragma unroll
      for (int j = 0; j < 2; ++j)
        acc[i][j] = __builtin_amdgcn_mfma_f32_16x16x32_bf16(af[i], bfv[j], acc[i][j], 0, 0, 0);
  }

  int mode = n0 >> 8;   // 0:Q 1:K 2:V (block-uniform)
  int r0 = quad * 4;
#pragma unroll
  for (int i = 0; i < 4; ++i) {
    int mbase = m0 + wm * 64 + i * 16 + r0;
#pragma unroll
    for (int j = 0; j < 2; ++j) {
      int n = n0 + wn * 32 + j * 16 + col;
#pragma unroll
      for (int r = 0; r < 4; ++r) {
        int m = mbase + r;
        float v = acc[i][j][r];
        if (mode == 0) {
          Qb[(size_t)m * CDIM + n] = f2bf(v);
        } else if (mode == 1) {
          Kb[(size_t)m * CDIM + (n - 256)] = f2bf(v);
        } else {
          int cv = n - 512, bb = m >> 12, nt = m & 4095;
          VT[((size_t)bb * CDIM + cv) * NTOK + nt] = f2bf(v);
        }
      }
    }
  }
}

// ---------------------------------------------------------------------------
// Fused attention, TWO-PASS exact softmax, DIRECT-FROM-L2 operands.
// Structure identical to R2/R3; every global->reg fragment is PINNED after
// load (pinv) to defeat load rematerialization, restoring the 2-deep
// register pipeline the structure was designed around.
// ---------------------------------------------------------------------------

#define P1_STEP(KF)                                                            \
  {                                                                            \
    f32x4 s0 = (f32x4){0.f, 0.f, 0.f, 0.f};                                    \
    f32x4 s1 = (f32x4){0.f, 0.f, 0.f, 0.f};                                    \
    _Pragma("unroll")                                                          \
    for (int kk = 0; kk < 8; ++kk) {                                           \
      s0 = __builtin_amdgcn_mfma_f32_16x16x32_bf16(aq[0][kk], KF[kk], s0, 0, 0, 0); \
      s1 = __builtin_amdgcn_mfma_f32_16x16x32_bf16(aq[1][kk], KF[kk], s1, 0, 0, 0); \
    }                                                                          \
    float mn0[4], mn1[4];                                                      \
    bool chg = false;                                                          \
    _Pragma("unroll")                                                          \
    for (int r = 0; r < 4; ++r) {                                              \
      mn0[r] = fmaxf(ml[0][r], s0[r]);                                         \
      mn1[r] = fmaxf(ml[1][r], s1[r]);                                         \
      chg = chg || (mn0[r] > ml[0][r]) || (mn1[r] > ml[1][r]);                 \
    }                                                                          \
    if (__any(chg)) {                                                          \
      _Pragma("unroll")                                                        \
      for (int r = 0; r < 4; ++r) {                                            \
        ll[0][r] = ll[0][r] * fexp2(ml[0][r] - mn0[r]) + fexp2(s0[r] - mn0[r]);\
        ml[0][r] = mn0[r];                                                     \
        ll[1][r] = ll[1][r] * fexp2(ml[1][r] - mn1[r]) + fexp2(s1[r] - mn1[r]);\
        ml[1][r] = mn1[r];                                                     \
      }                                                                        \
    } else {                                                                   \
      _Pragma("unroll")                                                        \
      for (int r = 0; r < 4; ++r) {                                            \
        ll[0][r] += fexp2(s0[r] - ml[0][r]);                                   \
        ll[1][r] += fexp2(s1[r] - ml[1][r]);                                   \
      }                                                                        \
    }                                                                          \
  }

#define S_COMPUTE(BK_)                                                         \
  {                                                                            \
    s0 = (f32x4){0.f, 0.f, 0.f, 0.f};                                          \
    s1 = (f32x4){0.f, 0.f, 0.f, 0.f};                                          \
    _Pragma("unroll")                                                          \
    for (int kk = 0; kk < 8; ++kk) {                                           \
      s0 = __builtin_amdgcn_mfma_f32_16x16x32_bf16(aq[0][kk], BK_[kk], s0, 0, 0, 0); \
      s1 = __builtin_amdgcn_mfma_f32_16x16x32_bf16(aq[1][kk], BK_[kk], s1, 0, 0, 0); \
    }                                                                          \
  }

#define P_WRITE(PN)                                                            \
  {                                                                            \
    _Pragma("unroll")                                                          \
    for (int r = 0; r < 4; ++r) {                                              \
      float sv0 = s0[r];                                                       \
      float rl0 = sv0 > 0.f ? sv0 * sv0 : 0.f;                                 \
      float p0 = c1[0][r] * fexp2(sv0 - mf[0][r]) + a2p * rl0;                 \
      int qr0 = quad * 4 + r;                                                  \
      int sl0 = ((w * 2 + (col >> 3)) ^ qr0) & 7;                              \
      (PN)[qr0 * 64 + sl0 * 8 + (col & 7)] = f2bf(p0);                         \
      float sv1 = s1[r];                                                       \
      float rl1 = sv1 > 0.f ? sv1 * sv1 : 0.f;                                 \
      float p1 = c1[1][r] * fexp2(sv1 - mf[1][r]) + a2p * rl1;                 \
      int qr1 = 16 + quad * 4 + r;                                             \
      int sl1 = ((w * 2 + (col >> 3)) ^ qr1) & 7;                              \
      (PN)[qr1 * 64 + sl1 * 8 + (col & 7)] = f2bf(p1);                         \
    }                                                                          \
  }

__global__ __launch_bounds__(256, 2) void fa_kernel(const u16* __restrict__ Qg,
                                                    const u16* __restrict__ Kg,
                                                    const u16* __restrict__ Vtg,
                                                    const u16* __restrict__ xng,
                                                    const float* __restrict__ w1p,
                                                    const float* __restrict__ w2p,
                                                    float* __restrict__ outg) {
  // epilogue otile [256][36] f32 = 36864 B dominates; P/stat usage is smaller
  __shared__ __align__(16) char smem[36864];
  float* otile = (float*)smem;
  u16* Pb0 = (u16*)smem;                 // [32][64] bf16, 16B-slot XOR swizzle
  u16* Pb1 = Pb0 + 2048;
  float* mbuf = (float*)(smem + 8192);   // [4 waves][32 q]
  float* lbuf = mbuf + 128;

  int b  = blockIdx.x & 3;               // XCD swizzle: same XCD -> same batch
  int q0 = (blockIdx.x >> 2) * 32;

  const u16* Q  = Qg  + (size_t)b * NTOK * CDIM;
  const u16* K  = Kg  + (size_t)b * NTOK * CDIM;
  const u16* Vt = Vtg + (size_t)b * NTOK * CDIM;

  int tid  = threadIdx.x;
  int lane = tid & 63;
  int w    = tid >> 6;                   // wave = key quarter
  int col = lane & 15, quad = lane >> 4;

  float e1 = __expf(w1p[0]), e2 = __expf(w2p[0]);
  float a1 = e1 / (e1 + e2), a2 = e2 / (e1 + e2);
  float a2p = a2 * 0.4804530139182014f;  // a2 * ln2^2 (S in exp2 domain)

  // ---- Q A-frags for BOTH q-groups (64 VGPR), live through both passes ----
  bf16x8 aq[2][8];
#pragma unroll
  for (int g = 0; g < 2; ++g)
#pragma unroll
    for (int kk = 0; kk < 8; ++kk) {
      aq[g][kk] = *(const bf16x8*)&Q[(size_t)(q0 + g * 16 + col) * CDIM + kk * 32 + quad * 8];
      pinv(aq[g][kk]);
    }

  // per-lane global bases: K rows = keys (this wave's 16), VT rows = channels
  const u16* kbase = K  + (size_t)(w * 16 + col) * CDIM + quad * 8;
  const u16* vbase = Vt + (size_t)(w * 64 + col) * NTOK + quad * 8;

  // =========================== PASS 1: m, l ================================
  float ml[2][4], ll[2][4];
#pragma unroll
  for (int g = 0; g < 2; ++g)
#pragma unroll
    for (int r = 0; r < 4; ++r) { ml[g][r] = -3e38f; ll[g][r] = 0.f; }

  bf16x8 kf0[8], kf1[8];
#pragma unroll
  for (int kk = 0; kk < 8; ++kk) {
    kf0[kk] = *(const bf16x8*)(kbase + kk * 32);
    pinv(kf0[kk]);
  }

  for (int t = 0; t < 64; t += 2) {
#pragma unroll
    for (int kk = 0; kk < 8; ++kk) {
      kf1[kk] = *(const bf16x8*)(kbase + (size_t)(t + 1) * 16384 + kk * 32);
      pinv(kf1[kk]);
    }
    P1_STEP(kf0)
    if (t + 2 < 64) {
#pragma unroll
      for (int kk = 0; kk < 8; ++kk) {
        kf0[kk] = *(const bf16x8*)(kbase + (size_t)(t + 2) * 16384 + kk * 32);
        pinv(kf0[kk]);
      }
    }
    P1_STEP(kf1)
  }

  // merge across the 16 cols of this wave (keys within quarter)
#pragma unroll
  for (int off = 1; off < 16; off <<= 1)
#pragma unroll
    for (int g = 0; g < 2; ++g)
#pragma unroll
      for (int r = 0; r < 4; ++r) {
        float mo = __shfl_xor(ml[g][r], off);
        float lo = __shfl_xor(ll[g][r], off);
        float mn = fmaxf(ml[g][r], mo);
        ll[g][r] = ll[g][r] * fexp2(ml[g][r] - mn) + lo * fexp2(mo - mn);
        ml[g][r] = mn;
      }
  // merge across the 4 waves (key quarters) via LDS, once
  if (col == 0) {
#pragma unroll
    for (int g = 0; g < 2; ++g)
#pragma unroll
      for (int r = 0; r < 4; ++r) {
        int qr = g * 16 + quad * 4 + r;
        mbuf[w * 32 + qr] = ml[g][r];
        lbuf[w * 32 + qr] = ll[g][r];
      }
  }
  __syncthreads();
  float mf[2][4], c1[2][4];
#pragma unroll
  for (int g = 0; g < 2; ++g)
#pragma unroll
    for (int r = 0; r < 4; ++r) {
      int qr = g * 16 + quad * 4 + r;
      float M = -3e38f, L = 0.f;
#pragma unroll
      for (int ww = 0; ww < 4; ++ww) {
        float mo = mbuf[ww * 32 + qr];
        float lo = lbuf[ww * 32 + qr];
        float mn = fmaxf(M, mo);
        L = L * fexp2(M - mn) + lo * fexp2(mo - mn);
        M = mn;
      }
      mf[g][r] = M;
      c1[g][r] = a1 / L;
    }

  // =========================== PASS 2: P, O ================================
  f32x4 o[2][4];
#pragma unroll
  for (int g = 0; g < 2; ++g)
#pragma unroll
    for (int j = 0; j < 4; ++j) o[g][j] = (f32x4){0.f, 0.f, 0.f, 0.f};

  bf16x8 bk[8], bv[8];
  // prologue: bk(0), S(0), P write -> Pb0, bv(0), barrier
#pragma unroll
  for (int kk = 0; kk < 8; ++kk) {
    bk[kk] = *(const bf16x8*)(kbase + kk * 32);
    pinv(bk[kk]);
  }
  {
    f32x4 s0, s1;
    S_COMPUTE(bk)
    P_WRITE(Pb0)
  }
#pragma unroll
  for (int j = 0; j < 4; ++j)
#pragma unroll
    for (int ks = 0; ks < 2; ++ks) {
      bv[j * 2 + ks] = *(const bf16x8*)(vbase + (size_t)j * 16 * NTOK + ks * 32);
      pinv(bv[j * 2 + ks]);
    }
  asm volatile("s_waitcnt lgkmcnt(0)\n\ts_barrier" ::: "memory");
  __builtin_amdgcn_sched_barrier(0);

  for (int t = 0; t < 64; ++t) {
    u16* Pc = (t & 1) ? Pb1 : Pb0;
    // pa reads (swizzled)
    bf16x8 pa[2][2];
#pragma unroll
    for (int g = 0; g < 2; ++g)
#pragma unroll
      for (int ks = 0; ks < 2; ++ks)
        pa[g][ks] = *(const bf16x8*)&Pc[(g * 16 + col) * 64 +
                                        (((quad + ks * 4) ^ (col & 7)) & 7) * 8];
    // bk(t+1) issue (hidden under PV)
    if (t < 63) {
#pragma unroll
      for (int kk = 0; kk < 8; ++kk) {
        bk[kk] = *(const bf16x8*)(kbase + (size_t)(t + 1) * 16384 + kk * 32);
        pinv(bk[kk]);
      }
    }
    // PV(t): 16 MFMAs, full 64 keys x this wave's 64 channels x 32 q
#pragma unroll
    for (int g = 0; g < 2; ++g)
#pragma unroll
      for (int j = 0; j < 4; ++j) {
        o[g][j] = __builtin_amdgcn_mfma_f32_16x16x32_bf16(pa[g][0], bv[j * 2 + 0], o[g][j], 0, 0, 0);
        o[g][j] = __builtin_amdgcn_mfma_f32_16x16x32_bf16(pa[g][1], bv[j * 2 + 1], o[g][j], 0, 0, 0);
      }
    if (t < 63) {
      // bv(t+1) issue (hidden under S)
#pragma unroll
      for (int j = 0; j < 4; ++j)
#pragma unroll
        for (int ks = 0; ks < 2; ++ks) {
          bv[j * 2 + ks] = *(const bf16x8*)(vbase + (size_t)j * 16 * NTOK +
                                            (size_t)(t + 1) * 64 + ks * 32);
          pinv(bv[j * 2 + ks]);
        }
      // S(t+1): 16 MFMAs on this wave's 16 keys
      f32x4 s0, s1;
      S_COMPUTE(bk)
      P_WRITE((t & 1) ? Pb0 : Pb1)
      asm volatile("s_waitcnt lgkmcnt(0)\n\ts_barrier" ::: "memory");
      __builtin_amdgcn_sched_barrier(0);
    }
  }

  // ---- epilogue: residual + transpose to [c][n] ----
  __syncthreads();   // all waves done with P before otile overlays it
#pragma unroll
  for (int g = 0; g < 2; ++g)
#pragma unroll
    for (int j = 0; j < 4; ++j) {
      int c = w * 64 + j * 16 + col;
      float4 v4;
      float* vv = (float*)&v4;
#pragma unroll
      for (int r = 0; r < 4; ++r) {
        int row = g * 16 + quad * 4 + r;
        vv[r] = o[g][j][r] + bf2f(xng[((size_t)b * NTOK + q0 + row) * CDIM + c]);
      }
      *(float4*)&otile[(size_t)c * 36 + g * 16 + quad * 4] = v4;
    }
  __syncthreads();

#pragma unroll
  for (int it = 0; it < 8; ++it) {
    int c  = it * 32 + (tid >> 3);
    int ch = tid & 7;
    *(float4*)&outg[((size_t)b * CDIM + c) * NTOK + q0 + ch * 4] =
        *(const float4*)&otile[(size_t)c * 36 + ch * 4];
  }
}

// ---------------------------------------------------------------------------
extern "C" void kernel_launch(void* const* d_in, const int* in_sizes, int n_in,
                              void* d_out, int out_size, void* d_ws, size_t ws_size,
                              hipStream_t stream) {
  const float* x     = (const float*)d_in[0];
  const float* gamma = (const float*)d_in[1];
  const float* beta  = (const float*)d_in[2];
  const float* Wq    = (const float*)d_in[3];
  const float* Wk    = (const float*)d_in[4];
  const float* Wv    = (const float*)d_in[5];
  const float* w1    = (const float*)d_in[6];
  const float* w2    = (const float*)d_in[7];
  float* out = (float*)d_out;

  char* ws = (char*)d_ws;
  size_t off = 0;
  u16* xn  = (u16*)(ws + off); off += (size_t)BATCH * NTOK * CDIM * 2;
  u16* WT3 = (u16*)(ws + off); off += (size_t)3 * CDIM * CDIM * 2;   // [768][256]
  u16* Qb  = (u16*)(ws + off); off += (size_t)BATCH * NTOK * CDIM * 2;
  u16* Kb  = (u16*)(ws + off); off += (size_t)BATCH * NTOK * CDIM * 2;
  u16* VT  = (u16*)(ws + off); off += (size_t)BATCH * NTOK * CDIM * 2;  // [b][c][n]

  const float LOG2E = 1.4426950408889634f;

  // 1) LayerNorm -> xn bf16 [B*N, C]
  ln_kernel<<<dim3(BATCH * (NTOK / 32)), 256, 0, stream>>>(x, gamma, beta, xn);

  // 2) stacked transposed weights (Wq pre-scaled by log2e -> exp2-domain S)
  wt_kernel<<<dim3(8, 8), dim3(32, 8), 0, stream>>>(Wq, WT3, LOG2E);
  wt_kernel<<<dim3(8, 8), dim3(32, 8), 0, stream>>>(Wk, WT3 + 256 * 256, 1.0f);
  wt_kernel<<<dim3(8, 8), dim3(32, 8), 0, stream>>>(Wv, WT3 + 512 * 256, 1.0f);

  // 3) fused Q/K/V projection (one launch)
  qkv_kernel<<<dim3(12, 128), 256, 0, stream>>>(xn, WT3, Qb, Kb, VT);

  // 4) fused attention (two-pass, direct-from-L2, remat-pinned) + epilogue
  fa_kernel<<<dim3(512), 256, 0, stream>>>(Qb, Kb, VT, xn, w1, w2, out);
}

// Round 5
// 299.211 us; speedup vs baseline: 1.7475x; 1.7475x over previous
//
#include <hip/hip_runtime.h>
#include <hip/hip_bf16.h>
#include <cstdint>

typedef unsigned short u16;
typedef __attribute__((ext_vector_type(8))) short bf16x8;
typedef __attribute__((ext_vector_type(4))) float f32x4;

#define BATCH 4
#define CDIM 256
#define NTOK 4096   // H*W

__device__ inline float fexp2(float x) { return __builtin_amdgcn_exp2f(x); }

__device__ inline u16 f2bf(float f) {
  union { float f; uint32_t u; } un; un.f = f;
  uint32_t u = un.u;
  u += 0x7fffu + ((u >> 16) & 1u);
  return (u16)(u >> 16);
}
__device__ inline float bf2f(u16 h) {
  union { uint32_t u; float f; } un; un.u = ((uint32_t)h) << 16; return un.f;
}

__device__ inline void gload_lds16(const u16* g, u16* l) {
  __builtin_amdgcn_global_load_lds((const __attribute__((address_space(1))) void*)g,
                                   (__attribute__((address_space(3))) void*)l, 16, 0, 0);
}

// ---------------------------------------------------------------------------
// LayerNorm: x [B, C, N] -> xn bf16 [B*N, C]
// ---------------------------------------------------------------------------
__global__ __launch_bounds__(256) void ln_kernel(const float* __restrict__ x,
                                                 const float* __restrict__ gamma,
                                                 const float* __restrict__ beta,
                                                 u16* __restrict__ xn) {
  __shared__ float tile[CDIM][33];
  __shared__ float reds[8][32];
  __shared__ float reds2[8][32];
  __shared__ float mu_s[32], rs_s[32];

  int b  = blockIdx.x >> 7;
  int n0 = (blockIdx.x & 127) * 32;
  const float* xb = x + (size_t)b * CDIM * NTOK;

  int t = threadIdx.x & 31;
  int g = threadIdx.x >> 5;

  for (int c = g; c < CDIM; c += 8)
    tile[c][t] = xb[(size_t)c * NTOK + n0 + t];
  __syncthreads();

  float s = 0.f, s2 = 0.f;
  for (int c = g * 32; c < g * 32 + 32; ++c) {
    float v = tile[c][t];
    s += v; s2 += v * v;
  }
  reds[g][t] = s; reds2[g][t] = s2;
  __syncthreads();
  if (threadIdx.x < 32) {
    float ts = 0.f, ts2 = 0.f;
    for (int gg = 0; gg < 8; ++gg) { ts += reds[gg][threadIdx.x]; ts2 += reds2[gg][threadIdx.x]; }
    float mu = ts / CDIM;
    float var = ts2 / CDIM - mu * mu;
    mu_s[threadIdx.x] = mu;
    rs_s[threadIdx.x] = rsqrtf(var + 1e-5f);
  }
  __syncthreads();

  int c = threadIdx.x;
  float gam = gamma[c], bet = beta[c];
  u16* out = xn + ((size_t)b * NTOK + n0) * CDIM;
  for (int tt = 0; tt < 32; ++tt) {
    float v = tile[c][tt];
    float y = (v - mu_s[tt]) * rs_s[tt] * gam + bet;
    out[(size_t)tt * CDIM + c] = f2bf(y);
  }
}

// ---------------------------------------------------------------------------
// W [K, Cout] fp32 -> WT bf16 [Cout, K], optional scale (log2e for Wq)
// ---------------------------------------------------------------------------
__global__ __launch_bounds__(256) void wt_kernel(const float* __restrict__ W,
                                                 u16* __restrict__ WT,
                                                 float scale) {
  __shared__ float tile[32][33];
  int i0 = blockIdx.y * 32;
  int j0 = blockIdx.x * 32;
  int tx = threadIdx.x, ty = threadIdx.y;
  for (int r = ty; r < 32; r += 8)
    tile[r][tx] = W[(size_t)(i0 + r) * CDIM + j0 + tx];
  __syncthreads();
  for (int r = ty; r < 32; r += 8)
    WT[(size_t)(j0 + r) * CDIM + i0 + tx] = f2bf(tile[tx][r] * scale);
}

// ---------------------------------------------------------------------------
// Fused QKV projection (unchanged)
// ---------------------------------------------------------------------------
__global__ __launch_bounds__(256) void qkv_kernel(const u16* __restrict__ A,
                                                  const u16* __restrict__ B3,
                                                  u16* __restrict__ Qb,
                                                  u16* __restrict__ Kb,
                                                  u16* __restrict__ VT) {
  constexpr int BM = 128, BN = 64, BK = 32;
  __shared__ u16 shA[BM][BK + 8];
  __shared__ u16 shB[BN][BK + 8];

  int m0 = blockIdx.y * BM;
  int n0 = blockIdx.x * BN;

  int tid  = threadIdx.x;
  int lane = tid & 63;
  int wave = tid >> 6;
  int wm = wave >> 1, wn = wave & 1;
  int col  = lane & 15;
  int quad = lane >> 4;

  f32x4 acc[4][2];
#pragma unroll
  for (int i = 0; i < 4; ++i)
#pragma unroll
    for (int j = 0; j < 2; ++j) acc[i][j] = (f32x4){0.f, 0.f, 0.f, 0.f};

  for (int kb = 0; kb < CDIM; kb += BK) {
    __syncthreads();
#pragma unroll
    for (int c = tid; c < BM * BK / 8; c += 256) {
      int row = c >> 2, kc = c & 3;
      *(uint4*)&shA[row][kc * 8] = *(const uint4*)&A[(size_t)(m0 + row) * CDIM + kb + kc * 8];
    }
#pragma unroll
    for (int c = tid; c < BN * BK / 8; c += 256) {
      int row = c >> 2, kc = c & 3;
      *(uint4*)&shB[row][kc * 8] = *(const uint4*)&B3[(size_t)(n0 + row) * CDIM + kb + kc * 8];
    }
    __syncthreads();

    bf16x8 af[4], bfv[2];
#pragma unroll
    for (int i = 0; i < 4; ++i)
      af[i] = *(const bf16x8*)&shA[wm * 64 + i * 16 + col][quad * 8];
#pragma unroll
    for (int j = 0; j < 2; ++j)
      bfv[j] = *(const bf16x8*)&shB[wn * 32 + j * 16 + col][quad * 8];
#pragma unroll
    for (int i = 0; i < 4; ++i)
#pragma unroll
      for (int j = 0; j < 2; ++j)
        acc[i][j] = __builtin_amdgcn_mfma_f32_16x16x32_bf16(af[i], bfv[j], acc[i][j], 0, 0, 0);
  }

  int mode = n0 >> 8;   // 0:Q 1:K 2:V (block-uniform)
  int r0 = quad * 4;
#pragma unroll
  for (int i = 0; i < 4; ++i) {
    int mbase = m0 + wm * 64 + i * 16 + r0;
#pragma unroll
    for (int j = 0; j < 2; ++j) {
      int n = n0 + wn * 32 + j * 16 + col;
#pragma unroll
      for (int r = 0; r < 4; ++r) {
        int m = mbase + r;
        float v = acc[i][j][r];
        if (mode == 0) {
          Qb[(size_t)m * CDIM + n] = f2bf(v);
        } else if (mode == 1) {
          Kb[(size_t)m * CDIM + (n - 256)] = f2bf(v);
        } else {
          int cv = n - 512, bb = m >> 12, nt = m & 4095;
          VT[((size_t)bb * CDIM + cv) * NTOK + nt] = f2bf(v);
        }
      }
    }
  }
}

// ---------------------------------------------------------------------------
// Fused attention, TWO-PASS exact softmax. R1's staged-LDS structure (proven
// codegen) with LDS-traffic cuts:
//  - Pass 1: 4-way key split — each wave holds BOTH q-groups' Q and reads
//    only its own 16 keys' B-frags (reads 64->32 KB per 64-key tile).
//  - Pass 2: producer/consumer waves — waves 0,1 compute S+P (16 keys each,
//    both q-groups); waves 2,3 do PV only (128 channels each, both q-groups,
//    full 32-key P from LDS). bk reads halved, bv reads halved.
//  - Single __syncthreads per pass-2 iteration: producers run one tile ahead
//    (S(t+1) while consumers do PV(t)); K staged two tiles ahead, V one,
//    P double-buffered. Every cross-wave hazard crosses that one barrier.
// ---------------------------------------------------------------------------

// Online-softmax update for both q-groups from named frag bank KF.
#define P1_STEP(KF)                                                            \
  {                                                                            \
    f32x4 s0 = (f32x4){0.f, 0.f, 0.f, 0.f};                                    \
    f32x4 s1 = (f32x4){0.f, 0.f, 0.f, 0.f};                                    \
    _Pragma("unroll")                                                          \
    for (int kk = 0; kk < 8; ++kk) {                                           \
      s0 = __builtin_amdgcn_mfma_f32_16x16x32_bf16(aq[0][kk], KF[kk], s0, 0, 0, 0); \
      s1 = __builtin_amdgcn_mfma_f32_16x16x32_bf16(aq[1][kk], KF[kk], s1, 0, 0, 0); \
    }                                                                          \
    float mn0[4], mn1[4];                                                      \
    bool chg = false;                                                          \
    _Pragma("unroll")                                                          \
    for (int r = 0; r < 4; ++r) {                                              \
      mn0[r] = fmaxf(ml[0][r], s0[r]);                                         \
      mn1[r] = fmaxf(ml[1][r], s1[r]);                                         \
      chg = chg || (mn0[r] > ml[0][r]) || (mn1[r] > ml[1][r]);                 \
    }                                                                          \
    if (__any(chg)) {                                                          \
      _Pragma("unroll")                                                        \
      for (int r = 0; r < 4; ++r) {                                            \
        ll[0][r] = ll[0][r] * fexp2(ml[0][r] - mn0[r]) + fexp2(s0[r] - mn0[r]);\
        ml[0][r] = mn0[r];                                                     \
        ll[1][r] = ll[1][r] * fexp2(ml[1][r] - mn1[r]) + fexp2(s1[r] - mn1[r]);\
        ml[1][r] = mn1[r];                                                     \
      }                                                                        \
    } else {                                                                   \
      _Pragma("unroll")                                                        \
      for (int r = 0; r < 4; ++r) {                                            \
        ll[0][r] += fexp2(s0[r] - ml[0][r]);                                   \
        ll[1][r] += fexp2(s1[r] - ml[1][r]);                                   \
      }                                                                        \
    }                                                                          \
  }

// S for both q-groups from named frag bank BK_ into named s0/s1.
#define S_COMPUTE(BK_)                                                         \
  {                                                                            \
    s0 = (f32x4){0.f, 0.f, 0.f, 0.f};                                          \
    s1 = (f32x4){0.f, 0.f, 0.f, 0.f};                                          \
    _Pragma("unroll")                                                          \
    for (int kk = 0; kk < 8; ++kk) {                                           \
      s0 = __builtin_amdgcn_mfma_f32_16x16x32_bf16(aq[0][kk], BK_[kk], s0, 0, 0, 0); \
      s1 = __builtin_amdgcn_mfma_f32_16x16x32_bf16(aq[1][kk], BK_[kk], s1, 0, 0, 0); \
    }                                                                          \
  }

// Combined P (both q-groups) -> P buffer [32 q][40] u16, keys w*16+col.
#define P2_WRITE(PN)                                                           \
  {                                                                            \
    _Pragma("unroll")                                                          \
    for (int r = 0; r < 4; ++r) {                                              \
      float sv0 = s0[r];                                                       \
      float rl0 = sv0 > 0.f ? sv0 * sv0 : 0.f;                                 \
      float p0v = c1[0][r] * fexp2(sv0 - mf[0][r]) + a2p * rl0;                \
      (PN)[(quad * 4 + r) * 40 + w * 16 + col] = f2bf(p0v);                    \
      float sv1 = s1[r];                                                       \
      float rl1 = sv1 > 0.f ? sv1 * sv1 : 0.f;                                 \
      float p1v = c1[1][r] * fexp2(sv1 - mf[1][r]) + a2p * rl1;                \
      (PN)[(16 + quad * 4 + r) * 40 + w * 16 + col] = f2bf(p1v);               \
    }                                                                          \
  }

__global__ __launch_bounds__(256, 2) void fa_kernel(const u16* __restrict__ Qg,
                                                    const u16* __restrict__ Kg,
                                                    const u16* __restrict__ Vtg,
                                                    const u16* __restrict__ xng,
                                                    const float* __restrict__ w1p,
                                                    const float* __restrict__ w2p,
                                                    float* __restrict__ outg) {
  // Layout: pass1 K tiles [64][256]x2 @0/@32768 (64KB).
  //         pass2 K [32][256]x2 @0/@16384, V [256][32]x2 @32768/@49152.
  //         P [32][40]x2 @65536/@68096. mbuf @70656, lbuf @71168.
  //         epilogue otile [256][36] f32 overlays @0.
  __shared__ __align__(16) char smem[71680];
  float* otile = (float*)smem;
  u16* pb0 = (u16*)(smem + 65536);
  u16* pb1 = (u16*)(smem + 68096);
  float* mbuf = (float*)(smem + 70656);   // [4 waves][32 q]
  float* lbuf = (float*)(smem + 71168);

  int b  = blockIdx.x & 3;               // XCD swizzle: same XCD -> same batch
  int q0 = (blockIdx.x >> 2) * 32;

  const u16* Q  = Qg  + (size_t)b * NTOK * CDIM;
  const u16* K  = Kg  + (size_t)b * NTOK * CDIM;
  const u16* Vt = Vtg + (size_t)b * NTOK * CDIM;

  int tid  = threadIdx.x;
  int lane = tid & 63;
  int w    = tid >> 6;
  int col = lane & 15, quad = lane >> 4;

  float e1 = __expf(w1p[0]), e2 = __expf(w2p[0]);
  float a1 = e1 / (e1 + e2), a2 = e2 / (e1 + e2);
  float a2p = a2 * 0.4804530139182014f;  // a2 * ln2^2 (S in exp2 domain)

  // ---- Q A-frags for BOTH q-groups (64 VGPR), live through both passes ----
  bf16x8 aq[2][8];
#pragma unroll
  for (int g = 0; g < 2; ++g)
#pragma unroll
    for (int kk = 0; kk < 8; ++kk)
      aq[g][kk] = *(const bf16x8*)&Q[(size_t)(q0 + g * 16 + col) * CDIM + kk * 32 + quad * 8];

  // ---- precomputed per-thread staging offsets (u16 elements) ----
  int koff1[8];
#pragma unroll
  for (int it = 0; it < 8; ++it) {
    int row = it * 8 + (tid >> 5);
    int ch  = (tid & 31) ^ (row & 31);
    koff1[it] = row * CDIM + ch * 8;
  }
  int koff2[4], voff2[4];
#pragma unroll
  for (int it = 0; it < 4; ++it) {
    int row = it * 8 + (tid >> 5);
    int ch  = (tid & 31) ^ row;           // row < 32
    koff2[it] = row * CDIM + ch * 8;
    int vr  = it * 64 + (tid >> 2);
    int vch = (tid & 3) ^ ((vr >> 1) & 3);
    voff2[it] = vr * NTOK + vch * 8;
  }

  // =========================== PASS 1: m, l ================================
  u16* ka = (u16*)smem;            // K tile 64: [64][256] u16 = 32 KB
  u16* kb = ka + 16384;

  auto stage1 = [&](int n1, u16* Kdst) {
    const u16* kgb = K + (size_t)n1 * CDIM;
#pragma unroll
    for (int it = 0; it < 8; ++it)
      gload_lds16(kgb + koff1[it], Kdst + (size_t)(it * 256 + w * 64) * 8);
  };

  stage1(0, ka);

  float ml[2][4], ll[2][4];
#pragma unroll
  for (int g = 0; g < 2; ++g)
#pragma unroll
    for (int r = 0; r < 4; ++r) { ml[g][r] = -3e38f; ll[g][r] = 0.f; }

  __syncthreads();

  int kr1 = w * 16 + col;   // this wave's 16 keys within the 64-key tile
  for (int t = 0; t < 64; ++t) {
    if (t < 63) stage1((t + 1) * 64, kb);

    bf16x8 bkf[8];
#pragma unroll
    for (int kk = 0; kk < 8; ++kk)
      bkf[kk] = *(const bf16x8*)&ka[(size_t)kr1 * 256 + (((kk * 4 + quad) ^ kr1) & 31) * 8];
    P1_STEP(bkf)

    __syncthreads();
    u16* tk = ka; ka = kb; kb = tk;
  }

  // merge across the 16 cols of this wave (keys within quarter)
#pragma unroll
  for (int off = 1; off < 16; off <<= 1)
#pragma unroll
    for (int g = 0; g < 2; ++g)
#pragma unroll
      for (int r = 0; r < 4; ++r) {
        float mo = __shfl_xor(ml[g][r], off);
        float lo = __shfl_xor(ll[g][r], off);
        float mn = fmaxf(ml[g][r], mo);
        ll[g][r] = ll[g][r] * fexp2(ml[g][r] - mn) + lo * fexp2(mo - mn);
        ml[g][r] = mn;
      }
  // merge across the 4 waves (key quarters) via LDS, once
  if (col == 0) {
#pragma unroll
    for (int g = 0; g < 2; ++g)
#pragma unroll
      for (int r = 0; r < 4; ++r) {
        int qr = g * 16 + quad * 4 + r;
        mbuf[w * 32 + qr] = ml[g][r];
        lbuf[w * 32 + qr] = ll[g][r];
      }
  }
  __syncthreads();
  float mf[2][4], c1[2][4];
#pragma unroll
  for (int g = 0; g < 2; ++g)
#pragma unroll
    for (int r = 0; r < 4; ++r) {
      int qr = g * 16 + quad * 4 + r;
      float M = -3e38f, L = 0.f;
#pragma unroll
      for (int ww = 0; ww < 4; ++ww) {
        float mo = mbuf[ww * 32 + qr];
        float lo = lbuf[ww * 32 + qr];
        float mn = fmaxf(M, mo);
        L = L * fexp2(M - mn) + lo * fexp2(mo - mn);
        M = mn;
      }
      mf[g][r] = M;
      c1[g][r] = a1 / L;
    }

  // =========================== PASS 2: P, O ================================
  u16* k2a = (u16*)smem;                 // [32][256] u16 = 16 KB
  u16* k2b = k2a + 8192;
  u16* v2a = (u16*)(smem + 32768);       // [256][32] u16 = 16 KB
  u16* v2b = v2a + 8192;

  auto stageK2 = [&](int n1, u16* Kdst) {
    const u16* kgb = K + (size_t)n1 * CDIM;
#pragma unroll
    for (int it = 0; it < 4; ++it)
      gload_lds16(kgb + koff2[it], Kdst + (size_t)(it * 256 + w * 64) * 8);
  };
  auto stageV2 = [&](int n1, u16* Vdst) {
    const u16* vgb = Vt + n1;
#pragma unroll
    for (int it = 0; it < 4; ++it)
      gload_lds16(vgb + voff2[it], Vdst + (size_t)(it * 256 + w * 64) * 8);
  };

  f32x4 o[2][8];
#pragma unroll
  for (int g = 0; g < 2; ++g)
#pragma unroll
    for (int j = 0; j < 8; ++j) o[g][j] = (f32x4){0.f, 0.f, 0.f, 0.f};

  int kr2 = w * 16 + col;   // producer keys within 32-key tile (w<2 only)
  int c2  = w - 2;          // consumer channel half (w>=2 only)

  // prologue: K(0); sync; S(0)->P(0); K(1),V(0); sync
  stageK2(0, k2a);
  __syncthreads();
  if (w < 2) {
    bf16x8 bk[8];
#pragma unroll
    for (int kk = 0; kk < 8; ++kk)
      bk[kk] = *(const bf16x8*)&k2a[(size_t)kr2 * 256 + (((kk * 4 + quad) ^ kr2) & 31) * 8];
    f32x4 s0, s1;
    S_COMPUTE(bk)
    P2_WRITE(pb0)
  }
  stageK2(32, k2b);
  stageV2(0, v2a);
  __syncthreads();

  for (int t = 0; t < 128; ++t) {
    if (t < 126) stageK2((t + 2) * 32, (t & 1) ? k2b : k2a);
    if (t < 127) stageV2((t + 1) * 32, ((t + 1) & 1) ? v2b : v2a);

    if (w < 2) {
      // producer: S(t+1) from K(t+1), P(t+1) -> pb[(t+1)&1]
      if (t < 127) {
        const u16* ksrc = ((t + 1) & 1) ? k2b : k2a;
        bf16x8 bk[8];
#pragma unroll
        for (int kk = 0; kk < 8; ++kk)
          bk[kk] = *(const bf16x8*)&ksrc[(size_t)kr2 * 256 + (((kk * 4 + quad) ^ kr2) & 31) * 8];
        f32x4 s0, s1;
        S_COMPUTE(bk)
        u16* pdst = ((t + 1) & 1) ? pb1 : pb0;
        P2_WRITE(pdst)
      }
    } else {
      // consumer: PV(t) from P(t), V(t)
      const u16* psrc = (t & 1) ? pb1 : pb0;
      const u16* vsrc = (t & 1) ? v2b : v2a;
      bf16x8 pa0 = *(const bf16x8*)&psrc[(size_t)(col) * 40 + quad * 8];
      bf16x8 pa1 = *(const bf16x8*)&psrc[(size_t)(16 + col) * 40 + quad * 8];
#pragma unroll
      for (int j = 0; j < 8; ++j) {
        int vr = c2 * 128 + j * 16 + col;
        bf16x8 bv = *(const bf16x8*)&vsrc[(size_t)vr * 32 + (quad ^ ((vr >> 1) & 3)) * 8];
        o[0][j] = __builtin_amdgcn_mfma_f32_16x16x32_bf16(pa0, bv, o[0][j], 0, 0, 0);
        o[1][j] = __builtin_amdgcn_mfma_f32_16x16x32_bf16(pa1, bv, o[1][j], 0, 0, 0);
      }
    }
    __syncthreads();   // P(t+1) published, staging landed, all reads of t done
  }

  // ---- epilogue: residual + transpose to [c][n] (consumers hold O) ----
  if (w >= 2) {
#pragma unroll
    for (int g = 0; g < 2; ++g)
#pragma unroll
      for (int j = 0; j < 8; ++j) {
        int c = c2 * 128 + j * 16 + col;
        float4 v4;
        float* vv = (float*)&v4;
#pragma unroll
        for (int r = 0; r < 4; ++r) {
          int row = g * 16 + quad * 4 + r;
          vv[r] = o[g][j][r] + bf2f(xng[((size_t)b * NTOK + q0 + row) * CDIM + c]);
        }
        *(float4*)&otile[(size_t)c * 36 + g * 16 + quad * 4] = v4;
      }
  }
  __syncthreads();

#pragma unroll
  for (int it = 0; it < 8; ++it) {
    int c  = it * 32 + (tid >> 3);
    int ch = tid & 7;
    *(float4*)&outg[((size_t)b * CDIM + c) * NTOK + q0 + ch * 4] =
        *(const float4*)&otile[(size_t)c * 36 + ch * 4];
  }
}

// ---------------------------------------------------------------------------
extern "C" void kernel_launch(void* const* d_in, const int* in_sizes, int n_in,
                              void* d_out, int out_size, void* d_ws, size_t ws_size,
                              hipStream_t stream) {
  const float* x     = (const float*)d_in[0];
  const float* gamma = (const float*)d_in[1];
  const float* beta  = (const float*)d_in[2];
  const float* Wq    = (const float*)d_in[3];
  const float* Wk    = (const float*)d_in[4];
  const float* Wv    = (const float*)d_in[5];
  const float* w1    = (const float*)d_in[6];
  const float* w2    = (const float*)d_in[7];
  float* out = (float*)d_out;

  char* ws = (char*)d_ws;
  size_t off = 0;
  u16* xn  = (u16*)(ws + off); off += (size_t)BATCH * NTOK * CDIM * 2;
  u16* WT3 = (u16*)(ws + off); off += (size_t)3 * CDIM * CDIM * 2;   // [768][256]
  u16* Qb  = (u16*)(ws + off); off += (size_t)BATCH * NTOK * CDIM * 2;
  u16* Kb  = (u16*)(ws + off); off += (size_t)BATCH * NTOK * CDIM * 2;
  u16* VT  = (u16*)(ws + off); off += (size_t)BATCH * NTOK * CDIM * 2;  // [b][c][n]

  const float LOG2E = 1.4426950408889634f;

  // 1) LayerNorm -> xn bf16 [B*N, C]
  ln_kernel<<<dim3(BATCH * (NTOK / 32)), 256, 0, stream>>>(x, gamma, beta, xn);

  // 2) stacked transposed weights (Wq pre-scaled by log2e -> exp2-domain S)
  wt_kernel<<<dim3(8, 8), dim3(32, 8), 0, stream>>>(Wq, WT3, LOG2E);
  wt_kernel<<<dim3(8, 8), dim3(32, 8), 0, stream>>>(Wk, WT3 + 256 * 256, 1.0f);
  wt_kernel<<<dim3(8, 8), dim3(32, 8), 0, stream>>>(Wv, WT3 + 512 * 256, 1.0f);

  // 3) fused Q/K/V projection (one launch)
  qkv_kernel<<<dim3(12, 128), 256, 0, stream>>>(xn, WT3, Qb, Kb, VT);

  // 4) fused attention (two-pass, staged LDS, producer/consumer pass 2)
  fa_kernel<<<dim3(512), 256, 0, stream>>>(Qb, Kb, VT, xn, w1, w2, out);
}

// Round 6
// 298.528 us; speedup vs baseline: 1.7515x; 1.0023x over previous
//
#include <hip/hip_runtime.h>
#include <hip/hip_bf16.h>
#include <cstdint>

typedef unsigned short u16;
typedef __attribute__((ext_vector_type(8))) short bf16x8;
typedef __attribute__((ext_vector_type(4))) float f32x4;

#define BATCH 4
#define CDIM 256
#define NTOK 4096   // H*W

__device__ inline float fexp2(float x) { return __builtin_amdgcn_exp2f(x); }

__device__ inline u16 f2bf(float f) {
  union { float f; uint32_t u; } un; un.f = f;
  uint32_t u = un.u;
  u += 0x7fffu + ((u >> 16) & 1u);
  return (u16)(u >> 16);
}
__device__ inline float bf2f(u16 h) {
  union { uint32_t u; float f; } un; un.u = ((uint32_t)h) << 16; return un.f;
}

__device__ inline void gload_lds16(const u16* g, u16* l) {
  __builtin_amdgcn_global_load_lds((const __attribute__((address_space(1))) void*)g,
                                   (__attribute__((address_space(3))) void*)l, 16, 0, 0);
}

// Counted waits: per-wave pipeline control (loads stay in flight across
// barriers; barriers drain LDS ops only).
__device__ inline void wait_vm8()   { asm volatile("s_waitcnt vmcnt(8)" ::: "memory"); }
__device__ inline void wait_vm0()   { asm volatile("s_waitcnt vmcnt(0)" ::: "memory"); }
__device__ inline void wait_lgkm0() { asm volatile("s_waitcnt lgkmcnt(0)" ::: "memory"); }
__device__ inline void barrier_lgkm() {
  asm volatile("s_waitcnt lgkmcnt(0)\n\ts_barrier" ::: "memory");
  __builtin_amdgcn_sched_barrier(0);
}

// ---------------------------------------------------------------------------
// LayerNorm: x [B, C, N] -> xn bf16 [B*N, C]
// ---------------------------------------------------------------------------
__global__ __launch_bounds__(256) void ln_kernel(const float* __restrict__ x,
                                                 const float* __restrict__ gamma,
                                                 const float* __restrict__ beta,
                                                 u16* __restrict__ xn) {
  __shared__ float tile[CDIM][33];
  __shared__ float reds[8][32];
  __shared__ float reds2[8][32];
  __shared__ float mu_s[32], rs_s[32];

  int b  = blockIdx.x >> 7;
  int n0 = (blockIdx.x & 127) * 32;
  const float* xb = x + (size_t)b * CDIM * NTOK;

  int t = threadIdx.x & 31;
  int g = threadIdx.x >> 5;

  for (int c = g; c < CDIM; c += 8)
    tile[c][t] = xb[(size_t)c * NTOK + n0 + t];
  __syncthreads();

  float s = 0.f, s2 = 0.f;
  for (int c = g * 32; c < g * 32 + 32; ++c) {
    float v = tile[c][t];
    s += v; s2 += v * v;
  }
  reds[g][t] = s; reds2[g][t] = s2;
  __syncthreads();
  if (threadIdx.x < 32) {
    float ts = 0.f, ts2 = 0.f;
    for (int gg = 0; gg < 8; ++gg) { ts += reds[gg][threadIdx.x]; ts2 += reds2[gg][threadIdx.x]; }
    float mu = ts / CDIM;
    float var = ts2 / CDIM - mu * mu;
    mu_s[threadIdx.x] = mu;
    rs_s[threadIdx.x] = rsqrtf(var + 1e-5f);
  }
  __syncthreads();

  int c = threadIdx.x;
  float gam = gamma[c], bet = beta[c];
  u16* out = xn + ((size_t)b * NTOK + n0) * CDIM;
  for (int tt = 0; tt < 32; ++tt) {
    float v = tile[c][tt];
    float y = (v - mu_s[tt]) * rs_s[tt] * gam + bet;
    out[(size_t)tt * CDIM + c] = f2bf(y);
  }
}

// ---------------------------------------------------------------------------
// W [K, Cout] fp32 -> WT bf16 [Cout, K], optional scale (log2e for Wq)
// ---------------------------------------------------------------------------
__global__ __launch_bounds__(256) void wt_kernel(const float* __restrict__ W,
                                                 u16* __restrict__ WT,
                                                 float scale) {
  __shared__ float tile[32][33];
  int i0 = blockIdx.y * 32;
  int j0 = blockIdx.x * 32;
  int tx = threadIdx.x, ty = threadIdx.y;
  for (int r = ty; r < 32; r += 8)
    tile[r][tx] = W[(size_t)(i0 + r) * CDIM + j0 + tx];
  __syncthreads();
  for (int r = ty; r < 32; r += 8)
    WT[(size_t)(j0 + r) * CDIM + i0 + tx] = f2bf(tile[tx][r] * scale);
}

// ---------------------------------------------------------------------------
// Fused QKV projection (unchanged)
// ---------------------------------------------------------------------------
__global__ __launch_bounds__(256) void qkv_kernel(const u16* __restrict__ A,
                                                  const u16* __restrict__ B3,
                                                  u16* __restrict__ Qb,
                                                  u16* __restrict__ Kb,
                                                  u16* __restrict__ VT) {
  constexpr int BM = 128, BN = 64, BK = 32;
  __shared__ u16 shA[BM][BK + 8];
  __shared__ u16 shB[BN][BK + 8];

  int m0 = blockIdx.y * BM;
  int n0 = blockIdx.x * BN;

  int tid  = threadIdx.x;
  int lane = tid & 63;
  int wave = tid >> 6;
  int wm = wave >> 1, wn = wave & 1;
  int col  = lane & 15;
  int quad = lane >> 4;

  f32x4 acc[4][2];
#pragma unroll
  for (int i = 0; i < 4; ++i)
#pragma unroll
    for (int j = 0; j < 2; ++j) acc[i][j] = (f32x4){0.f, 0.f, 0.f, 0.f};

  for (int kb = 0; kb < CDIM; kb += BK) {
    __syncthreads();
#pragma unroll
    for (int c = tid; c < BM * BK / 8; c += 256) {
      int row = c >> 2, kc = c & 3;
      *(uint4*)&shA[row][kc * 8] = *(const uint4*)&A[(size_t)(m0 + row) * CDIM + kb + kc * 8];
    }
#pragma unroll
    for (int c = tid; c < BN * BK / 8; c += 256) {
      int row = c >> 2, kc = c & 3;
      *(uint4*)&shB[row][kc * 8] = *(const uint4*)&B3[(size_t)(n0 + row) * CDIM + kb + kc * 8];
    }
    __syncthreads();

    bf16x8 af[4], bfv[2];
#pragma unroll
    for (int i = 0; i < 4; ++i)
      af[i] = *(const bf16x8*)&shA[wm * 64 + i * 16 + col][quad * 8];
#pragma unroll
    for (int j = 0; j < 2; ++j)
      bfv[j] = *(const bf16x8*)&shB[wn * 32 + j * 16 + col][quad * 8];
#pragma unroll
    for (int i = 0; i < 4; ++i)
#pragma unroll
      for (int j = 0; j < 2; ++j)
        acc[i][j] = __builtin_amdgcn_mfma_f32_16x16x32_bf16(af[i], bfv[j], acc[i][j], 0, 0, 0);
  }

  int mode = n0 >> 8;   // 0:Q 1:K 2:V (block-uniform)
  int r0 = quad * 4;
#pragma unroll
  for (int i = 0; i < 4; ++i) {
    int mbase = m0 + wm * 64 + i * 16 + r0;
#pragma unroll
    for (int j = 0; j < 2; ++j) {
      int n = n0 + wn * 32 + j * 16 + col;
#pragma unroll
      for (int r = 0; r < 4; ++r) {
        int m = mbase + r;
        float v = acc[i][j][r];
        if (mode == 0) {
          Qb[(size_t)m * CDIM + n] = f2bf(v);
        } else if (mode == 1) {
          Kb[(size_t)m * CDIM + (n - 256)] = f2bf(v);
        } else {
          int cv = n - 512, bb = m >> 12, nt = m & 4095;
          VT[((size_t)bb * CDIM + cv) * NTOK + nt] = f2bf(v);
        }
      }
    }
  }
}

// ---------------------------------------------------------------------------
// Fused attention, TWO-PASS exact softmax, WAVE-PRIVATE STAGING:
//  - Each wave stages (global_load_lds) into its own 16KB LDS region exactly
//    the K/V rows it alone reads -> NO cross-wave staging hazards.
//  - Pass 1: ZERO barriers. Per-wave depth-2 pipeline with counted
//    s_waitcnt vmcnt(8) (in-order vmcnt retirement => tile landed while the
//    next stays in flight).
//  - Pass 2: producer waves 0,1 (S+P, 16 keys each), consumer waves 2,3
//    (PV, 128 channels each). One s_barrier/iter draining LGKM ONLY (P
//    handoff); K/V stages fly across barriers, self-synced per wave.
//  - Math/key-assignment/swizzles/P-layout identical to R5 (verified).
// ---------------------------------------------------------------------------

#define P1_STEP(KF)                                                            \
  {                                                                            \
    f32x4 s0 = (f32x4){0.f, 0.f, 0.f, 0.f};                                    \
    f32x4 s1 = (f32x4){0.f, 0.f, 0.f, 0.f};                                    \
    _Pragma("unroll")                                                          \
    for (int kk = 0; kk < 8; ++kk) {                                           \
      s0 = __builtin_amdgcn_mfma_f32_16x16x32_bf16(aq[0][kk], KF[kk], s0, 0, 0, 0); \
      s1 = __builtin_amdgcn_mfma_f32_16x16x32_bf16(aq[1][kk], KF[kk], s1, 0, 0, 0); \
    }                                                                          \
    float mn0[4], mn1[4];                                                      \
    bool chg = false;                                                          \
    _Pragma("unroll")                                                          \
    for (int r = 0; r < 4; ++r) {                                              \
      mn0[r] = fmaxf(ml[0][r], s0[r]);                                         \
      mn1[r] = fmaxf(ml[1][r], s1[r]);                                         \
      chg = chg || (mn0[r] > ml[0][r]) || (mn1[r] > ml[1][r]);                 \
    }                                                                          \
    if (__any(chg)) {                                                          \
      _Pragma("unroll")                                                        \
      for (int r = 0; r < 4; ++r) {                                            \
        ll[0][r] = ll[0][r] * fexp2(ml[0][r] - mn0[r]) + fexp2(s0[r] - mn0[r]);\
        ml[0][r] = mn0[r];                                                     \
        ll[1][r] = ll[1][r] * fexp2(ml[1][r] - mn1[r]) + fexp2(s1[r] - mn1[r]);\
        ml[1][r] = mn1[r];                                                     \
      }                                                                        \
    } else {                                                                   \
      _Pragma("unroll")                                                        \
      for (int r = 0; r < 4; ++r) {                                            \
        ll[0][r] += fexp2(s0[r] - ml[0][r]);                                   \
        ll[1][r] += fexp2(s1[r] - ml[1][r]);                                   \
      }                                                                        \
    }                                                                          \
  }

#define S_COMPUTE(BK_)                                                         \
  {                                                                            \
    s0 = (f32x4){0.f, 0.f, 0.f, 0.f};                                          \
    s1 = (f32x4){0.f, 0.f, 0.f, 0.f};                                          \
    _Pragma("unroll")                                                          \
    for (int kk = 0; kk < 8; ++kk) {                                           \
      s0 = __builtin_amdgcn_mfma_f32_16x16x32_bf16(aq[0][kk], BK_[kk], s0, 0, 0, 0); \
      s1 = __builtin_amdgcn_mfma_f32_16x16x32_bf16(aq[1][kk], BK_[kk], s1, 0, 0, 0); \
    }                                                                          \
  }

#define P2_WRITE(PN)                                                           \
  {                                                                            \
    _Pragma("unroll")                                                          \
    for (int r = 0; r < 4; ++r) {                                              \
      float sv0 = s0[r];                                                       \
      float rl0 = sv0 > 0.f ? sv0 * sv0 : 0.f;                                 \
      float p0v = c1[0][r] * fexp2(sv0 - mf[0][r]) + a2p * rl0;                \
      (PN)[(quad * 4 + r) * 40 + w * 16 + col] = f2bf(p0v);                    \
      float sv1 = s1[r];                                                       \
      float rl1 = sv1 > 0.f ? sv1 * sv1 : 0.f;                                 \
      float p1v = c1[1][r] * fexp2(sv1 - mf[1][r]) + a2p * rl1;                \
      (PN)[(16 + quad * 4 + r) * 40 + w * 16 + col] = f2bf(p1v);               \
    }                                                                          \
  }

// Read this wave's 8 K-frags (local rows = col) from wave-private buffer.
#define RD_KFRAG(FR, BUFP)                                                     \
  _Pragma("unroll")                                                            \
  for (int kk = 0; kk < 8; ++kk)                                               \
    FR[kk] = *(const bf16x8*)((BUFP) + col * 256 + (((kk * 4 + quad) ^ col) & 31) * 8);

__global__ __launch_bounds__(256, 2) void fa_kernel(const u16* __restrict__ Qg,
                                                    const u16* __restrict__ Kg,
                                                    const u16* __restrict__ Vtg,
                                                    const u16* __restrict__ xng,
                                                    const float* __restrict__ w1p,
                                                    const float* __restrict__ w2p,
                                                    float* __restrict__ outg) {
  // Layout: wave w private region @ w*16384 (two 8KB bufs) — pass1 K tiles,
  //         pass2 K (producers w=0,1) or V (consumers w=2,3).
  //         pb0 @65536, pb1 @68096 ([32][40] u16 each). mbuf @70656,
  //         lbuf @71168. Epilogue otile [256][36] f32 overlays @0.
  __shared__ __align__(16) char smem[71680];
  float* otile = (float*)smem;
  u16* pb0 = (u16*)(smem + 65536);
  u16* pb1 = (u16*)(smem + 68096);
  float* mbuf = (float*)(smem + 70656);
  float* lbuf = (float*)(smem + 71168);

  int b  = blockIdx.x & 3;               // XCD swizzle: same XCD -> same batch
  int q0 = (blockIdx.x >> 2) * 32;

  const u16* Q  = Qg  + (size_t)b * NTOK * CDIM;
  const u16* K  = Kg  + (size_t)b * NTOK * CDIM;
  const u16* Vt = Vtg + (size_t)b * NTOK * CDIM;

  int tid  = threadIdx.x;
  int lane = tid & 63;
  int w    = tid >> 6;
  int col = lane & 15, quad = lane >> 4;

  u16* myreg = (u16*)(smem + w * 16384);   // wave-private (u16* , 8192 elems)

  float e1 = __expf(w1p[0]), e2 = __expf(w2p[0]);
  float a1 = e1 / (e1 + e2), a2 = e2 / (e1 + e2);
  float a2p = a2 * 0.4804530139182014f;  // a2 * ln2^2 (S in exp2 domain)

  // ---- Q A-frags for BOTH q-groups, live through both passes ----
  bf16x8 aq[2][8];
#pragma unroll
  for (int g = 0; g < 2; ++g)
#pragma unroll
    for (int kk = 0; kk < 8; ++kk)
      aq[g][kk] = *(const bf16x8*)&Q[(size_t)(q0 + g * 16 + col) * CDIM + kk * 32 + quad * 8];

  // ---- wave-private staging source offsets (u16 elems, swizzle-matched) ---
  // K rows (pass1 & pass2-producer): 16 rows x 256 cols; instr it covers
  // rows it*2+(lane>>5); slot s=lane&31 holds 16B-chunk g = s ^ row.
  int koffK[8];
#pragma unroll
  for (int it = 0; it < 8; ++it) {
    int rl = it * 2 + (lane >> 5);
    int g8 = (lane & 31) ^ rl;
    koffK[it] = (w * 16 + rl) * CDIM + g8 * 8;
  }
  // V rows (pass2-consumer, w>=2): 128 rows x 32 cols; instr it covers rows
  // it*16+(lane>>2); slot s=lane&3 holds chunk g = s ^ ((row>>1)&3).
  int voffV[8];
#pragma unroll
  for (int it = 0; it < 8; ++it) {
    int vrl = it * 16 + (lane >> 2);
    int g3 = (lane & 3) ^ ((vrl >> 1) & 3);
    voffV[it] = ((w - 2) * 128 + vrl) * NTOK + g3 * 8;   // only valid for w>=2
  }

  auto stK = [&](int n1, int bufsel) {     // n1 = key base of tile
    const u16* kgb = K + (size_t)n1 * CDIM;
    u16* dst = myreg + bufsel * 4096;
#pragma unroll
    for (int it = 0; it < 8; ++it)
      gload_lds16(kgb + koffK[it], dst + it * 512);
  };
  auto stV = [&](int n1, int bufsel) {     // n1 = key base of tile
    const u16* vgb = Vt + n1;
    u16* dst = myreg + bufsel * 4096;
#pragma unroll
    for (int it = 0; it < 8; ++it)
      gload_lds16(vgb + voffV[it], dst + it * 512);
  };

  // =========================== PASS 1: m, l ================================
  float ml[2][4], ll[2][4];
#pragma unroll
  for (int g = 0; g < 2; ++g)
#pragma unroll
    for (int r = 0; r < 4; ++r) { ml[g][r] = -3e38f; ll[g][r] = 0.f; }

  stK(0, 0);
  stK(64, 1);

  for (int t = 0; t < 64; ++t) {
    if (t < 63) wait_vm8(); else wait_vm0();
    bf16x8 fr[8];
    RD_KFRAG(fr, myreg + (t & 1) * 4096)
    wait_lgkm0();                      // frags in regs before overwriting buf
    if (t < 62) stK((t + 2) * 64, t & 1);
    P1_STEP(fr)
  }

  // pass-2 prologue stages: issue NOW so L2 latency hides under the merge.
  if (w < 2) { stK(0, 0); stK(32, 1); }
  else       { stV(0, 0); stV(32, 1); }

  // merge across the 16 cols of this wave (keys within quarter)
#pragma unroll
  for (int off = 1; off < 16; off <<= 1)
#pragma unroll
    for (int g = 0; g < 2; ++g)
#pragma unroll
      for (int r = 0; r < 4; ++r) {
        float mo = __shfl_xor(ml[g][r], off);
        float lo = __shfl_xor(ll[g][r], off);
        float mn = fmaxf(ml[g][r], mo);
        ll[g][r] = ll[g][r] * fexp2(ml[g][r] - mn) + lo * fexp2(mo - mn);
        ml[g][r] = mn;
      }
  // merge across the 4 waves (key quarters) via LDS, once
  if (col == 0) {
#pragma unroll
    for (int g = 0; g < 2; ++g)
#pragma unroll
      for (int r = 0; r < 4; ++r) {
        int qr = g * 16 + quad * 4 + r;
        mbuf[w * 32 + qr] = ml[g][r];
        lbuf[w * 32 + qr] = ll[g][r];
      }
  }
  __syncthreads();   // full drain once (also lands the pass-2 prologue stages)
  float mf[2][4], c1[2][4];
#pragma unroll
  for (int g = 0; g < 2; ++g)
#pragma unroll
    for (int r = 0; r < 4; ++r) {
      int qr = g * 16 + quad * 4 + r;
      float M = -3e38f, L = 0.f;
#pragma unroll
      for (int ww = 0; ww < 4; ++ww) {
        float mo = mbuf[ww * 32 + qr];
        float lo = lbuf[ww * 32 + qr];
        float mn = fmaxf(M, mo);
        L = L * fexp2(M - mn) + lo * fexp2(mo - mn);
        M = mn;
      }
      mf[g][r] = M;
      c1[g][r] = a1 / L;
    }

  // =========================== PASS 2: P, O ================================
  f32x4 o[2][8];
#pragma unroll
  for (int g = 0; g < 2; ++g)
#pragma unroll
    for (int j = 0; j < 8; ++j) o[g][j] = (f32x4){0.f, 0.f, 0.f, 0.f};

  // producer pre-loop: S(0) -> P(0)
  if (w < 2) {
    wait_vm0();   // K2(0)/K2(1) already drained by __syncthreads; no-op safety
    bf16x8 fr[8];
    RD_KFRAG(fr, myreg)
    wait_lgkm0();
    stK(2 * 32, 0);                       // K2(2) -> buf0
    f32x4 s0, s1;
    S_COMPUTE(fr)
    P2_WRITE(pb0)
  }
  barrier_lgkm();

  for (int t = 0; t < 128; ++t) {
    if (w < 2) {
      // producer: S(t+1) from own-staged K(t+1), P(t+1) -> pb[(t+1)&1]
      if (t < 127) {
        if (t < 126) wait_vm8(); else wait_vm0();
        bf16x8 fr[8];
        RD_KFRAG(fr, myreg + ((t + 1) & 1) * 4096)
        wait_lgkm0();
        if (t < 125) stK((t + 3) * 32, (t + 1) & 1);
        f32x4 s0, s1;
        __builtin_amdgcn_s_setprio(1);
        S_COMPUTE(fr)
        __builtin_amdgcn_s_setprio(0);
        P2_WRITE(((t + 1) & 1) ? pb1 : pb0)
      }
    } else {
      // consumer: PV(t) from P(t) and own-staged V(t)
      if (t < 127) wait_vm8(); else wait_vm0();
      const u16* psrc = (t & 1) ? pb1 : pb0;
      const u16* vsrc = myreg + (t & 1) * 4096;
      bf16x8 pa0 = *(const bf16x8*)&psrc[col * 40 + quad * 8];
      bf16x8 pa1 = *(const bf16x8*)&psrc[(16 + col) * 40 + quad * 8];
      bf16x8 bvf[8];
#pragma unroll
      for (int j = 0; j < 8; ++j) {
        int vrl = j * 16 + col;
        bvf[j] = *(const bf16x8*)&vsrc[vrl * 32 + ((quad ^ ((vrl >> 1) & 3)) & 3) * 8];
      }
      wait_lgkm0();
      if (t < 126) stV((t + 2) * 32, t & 1);
      __builtin_amdgcn_s_setprio(1);
#pragma unroll
      for (int j = 0; j < 8; ++j) {
        o[0][j] = __builtin_amdgcn_mfma_f32_16x16x32_bf16(pa0, bvf[j], o[0][j], 0, 0, 0);
        o[1][j] = __builtin_amdgcn_mfma_f32_16x16x32_bf16(pa1, bvf[j], o[1][j], 0, 0, 0);
      }
      __builtin_amdgcn_s_setprio(0);
    }
    barrier_lgkm();   // P handoff only — K/V stages stay in flight across it
  }

  // ---- epilogue: residual + transpose to [c][n] (consumers hold O) ----
  __syncthreads();   // full drain before otile overlays K/V regions
  if (w >= 2) {
    int c2 = w - 2;
#pragma unroll
    for (int g = 0; g < 2; ++g)
#pragma unroll
      for (int j = 0; j < 8; ++j) {
        int c = c2 * 128 + j * 16 + col;
        float4 v4;
        float* vv = (float*)&v4;
#pragma unroll
        for (int r = 0; r < 4; ++r) {
          int row = g * 16 + quad * 4 + r;
          vv[r] = o[g][j][r] + bf2f(xng[((size_t)b * NTOK + q0 + row) * CDIM + c]);
        }
        *(float4*)&otile[(size_t)c * 36 + g * 16 + quad * 4] = v4;
      }
  }
  __syncthreads();

#pragma unroll
  for (int it = 0; it < 8; ++it) {
    int c  = it * 32 + (tid >> 3);
    int ch = tid & 7;
    *(float4*)&outg[((size_t)b * CDIM + c) * NTOK + q0 + ch * 4] =
        *(const float4*)&otile[(size_t)c * 36 + ch * 4];
  }
}

// ---------------------------------------------------------------------------
extern "C" void kernel_launch(void* const* d_in, const int* in_sizes, int n_in,
                              void* d_out, int out_size, void* d_ws, size_t ws_size,
                              hipStream_t stream) {
  const float* x     = (const float*)d_in[0];
  const float* gamma = (const float*)d_in[1];
  const float* beta  = (const float*)d_in[2];
  const float* Wq    = (const float*)d_in[3];
  const float* Wk    = (const float*)d_in[4];
  const float* Wv    = (const float*)d_in[5];
  const float* w1    = (const float*)d_in[6];
  const float* w2    = (const float*)d_in[7];
  float* out = (float*)d_out;

  char* ws = (char*)d_ws;
  size_t off = 0;
  u16* xn  = (u16*)(ws + off); off += (size_t)BATCH * NTOK * CDIM * 2;
  u16* WT3 = (u16*)(ws + off); off += (size_t)3 * CDIM * CDIM * 2;   // [768][256]
  u16* Qb  = (u16*)(ws + off); off += (size_t)BATCH * NTOK * CDIM * 2;
  u16* Kb  = (u16*)(ws + off); off += (size_t)BATCH * NTOK * CDIM * 2;
  u16* VT  = (u16*)(ws + off); off += (size_t)BATCH * NTOK * CDIM * 2;  // [b][c][n]

  const float LOG2E = 1.4426950408889634f;

  // 1) LayerNorm -> xn bf16 [B*N, C]
  ln_kernel<<<dim3(BATCH * (NTOK / 32)), 256, 0, stream>>>(x, gamma, beta, xn);

  // 2) stacked transposed weights (Wq pre-scaled by log2e -> exp2-domain S)
  wt_kernel<<<dim3(8, 8), dim3(32, 8), 0, stream>>>(Wq, WT3, LOG2E);
  wt_kernel<<<dim3(8, 8), dim3(32, 8), 0, stream>>>(Wk, WT3 + 256 * 256, 1.0f);
  wt_kernel<<<dim3(8, 8), dim3(32, 8), 0, stream>>>(Wv, WT3 + 512 * 256, 1.0f);

  // 3) fused Q/K/V projection (one launch)
  qkv_kernel<<<dim3(12, 128), 256, 0, stream>>>(xn, WT3, Qb, Kb, VT);

  // 4) fused attention (two-pass, wave-private staging, counted vmcnt)
  fa_kernel<<<dim3(512), 256, 0, stream>>>(Qb, Kb, VT, xn, w1, w2, out);
}

// Round 7
// 283.991 us; speedup vs baseline: 1.8412x; 1.0512x over previous
//
#include <hip/hip_runtime.h>
#include <hip/hip_bf16.h>
#include <cstdint>

typedef unsigned short u16;
typedef __attribute__((ext_vector_type(8))) short bf16x8;
typedef __attribute__((ext_vector_type(4))) float f32x4;

#define BATCH 4
#define CDIM 256
#define NTOK 4096   // H*W

__device__ inline float fexp2(float x) { return __builtin_amdgcn_exp2f(x); }

__device__ inline u16 f2bf(float f) {
  union { float f; uint32_t u; } un; un.f = f;
  uint32_t u = un.u;
  u += 0x7fffu + ((u >> 16) & 1u);
  return (u16)(u >> 16);
}
__device__ inline float bf2f(u16 h) {
  union { uint32_t u; float f; } un; un.u = ((uint32_t)h) << 16; return un.f;
}

__device__ inline void gload_lds16(const u16* g, u16* l) {
  __builtin_amdgcn_global_load_lds((const __attribute__((address_space(1))) void*)g,
                                   (__attribute__((address_space(3))) void*)l, 16, 0, 0);
}

// ---------------------------------------------------------------------------
// LayerNorm: x [B, C, N] -> xn bf16 [B*N, C]
// ---------------------------------------------------------------------------
__global__ __launch_bounds__(256) void ln_kernel(const float* __restrict__ x,
                                                 const float* __restrict__ gamma,
                                                 const float* __restrict__ beta,
                                                 u16* __restrict__ xn) {
  __shared__ float tile[CDIM][33];
  __shared__ float reds[8][32];
  __shared__ float reds2[8][32];
  __shared__ float mu_s[32], rs_s[32];

  int b  = blockIdx.x >> 7;
  int n0 = (blockIdx.x & 127) * 32;
  const float* xb = x + (size_t)b * CDIM * NTOK;

  int t = threadIdx.x & 31;
  int g = threadIdx.x >> 5;

  for (int c = g; c < CDIM; c += 8)
    tile[c][t] = xb[(size_t)c * NTOK + n0 + t];
  __syncthreads();

  float s = 0.f, s2 = 0.f;
  for (int c = g * 32; c < g * 32 + 32; ++c) {
    float v = tile[c][t];
    s += v; s2 += v * v;
  }
  reds[g][t] = s; reds2[g][t] = s2;
  __syncthreads();
  if (threadIdx.x < 32) {
    float ts = 0.f, ts2 = 0.f;
    for (int gg = 0; gg < 8; ++gg) { ts += reds[gg][threadIdx.x]; ts2 += reds2[gg][threadIdx.x]; }
    float mu = ts / CDIM;
    float var = ts2 / CDIM - mu * mu;
    mu_s[threadIdx.x] = mu;
    rs_s[threadIdx.x] = rsqrtf(var + 1e-5f);
  }
  __syncthreads();

  int c = threadIdx.x;
  float gam = gamma[c], bet = beta[c];
  u16* out = xn + ((size_t)b * NTOK + n0) * CDIM;
  for (int tt = 0; tt < 32; ++tt) {
    float v = tile[c][tt];
    float y = (v - mu_s[tt]) * rs_s[tt] * gam + bet;
    out[(size_t)tt * CDIM + c] = f2bf(y);
  }
}

// ---------------------------------------------------------------------------
// W [K, Cout] fp32 -> WT bf16 [Cout, K], optional scale (log2e for Wq)
// ---------------------------------------------------------------------------
__global__ __launch_bounds__(256) void wt_kernel(const float* __restrict__ W,
                                                 u16* __restrict__ WT,
                                                 float scale) {
  __shared__ float tile[32][33];
  int i0 = blockIdx.y * 32;
  int j0 = blockIdx.x * 32;
  int tx = threadIdx.x, ty = threadIdx.y;
  for (int r = ty; r < 32; r += 8)
    tile[r][tx] = W[(size_t)(i0 + r) * CDIM + j0 + tx];
  __syncthreads();
  for (int r = ty; r < 32; r += 8)
    WT[(size_t)(j0 + r) * CDIM + i0 + tx] = f2bf(tile[tx][r] * scale);
}

// ---------------------------------------------------------------------------
// Fused QKV projection (unchanged)
// ---------------------------------------------------------------------------
__global__ __launch_bounds__(256) void qkv_kernel(const u16* __restrict__ A,
                                                  const u16* __restrict__ B3,
                                                  u16* __restrict__ Qb,
                                                  u16* __restrict__ Kb,
                                                  u16* __restrict__ VT) {
  constexpr int BM = 128, BN = 64, BK = 32;
  __shared__ u16 shA[BM][BK + 8];
  __shared__ u16 shB[BN][BK + 8];

  int m0 = blockIdx.y * BM;
  int n0 = blockIdx.x * BN;

  int tid  = threadIdx.x;
  int lane = tid & 63;
  int wave = tid >> 6;
  int wm = wave >> 1, wn = wave & 1;
  int col  = lane & 15;
  int quad = lane >> 4;

  f32x4 acc[4][2];
#pragma unroll
  for (int i = 0; i < 4; ++i)
#pragma unroll
    for (int j = 0; j < 2; ++j) acc[i][j] = (f32x4){0.f, 0.f, 0.f, 0.f};

  for (int kb = 0; kb < CDIM; kb += BK) {
    __syncthreads();
#pragma unroll
    for (int c = tid; c < BM * BK / 8; c += 256) {
      int row = c >> 2, kc = c & 3;
      *(uint4*)&shA[row][kc * 8] = *(const uint4*)&A[(size_t)(m0 + row) * CDIM + kb + kc * 8];
    }
#pragma unroll
    for (int c = tid; c < BN * BK / 8; c += 256) {
      int row = c >> 2, kc = c & 3;
      *(uint4*)&shB[row][kc * 8] = *(const uint4*)&B3[(size_t)(n0 + row) * CDIM + kb + kc * 8];
    }
    __syncthreads();

    bf16x8 af[4], bfv[2];
#pragma unroll
    for (int i = 0; i < 4; ++i)
      af[i] = *(const bf16x8*)&shA[wm * 64 + i * 16 + col][quad * 8];
#pragma unroll
    for (int j = 0; j < 2; ++j)
      bfv[j] = *(const bf16x8*)&shB[wn * 32 + j * 16 + col][quad * 8];
#pragma unroll
    for (int i = 0; i < 4; ++i)
#pragma unroll
      for (int j = 0; j < 2; ++j)
        acc[i][j] = __builtin_amdgcn_mfma_f32_16x16x32_bf16(af[i], bfv[j], acc[i][j], 0, 0, 0);
  }

  int mode = n0 >> 8;   // 0:Q 1:K 2:V (block-uniform)
  int r0 = quad * 4;
#pragma unroll
  for (int i = 0; i < 4; ++i) {
    int mbase = m0 + wm * 64 + i * 16 + r0;
#pragma unroll
    for (int j = 0; j < 2; ++j) {
      int n = n0 + wn * 32 + j * 16 + col;
#pragma unroll
      for (int r = 0; r < 4; ++r) {
        int m = mbase + r;
        float v = acc[i][j][r];
        if (mode == 0) {
          Qb[(size_t)m * CDIM + n] = f2bf(v);
        } else if (mode == 1) {
          Kb[(size_t)m * CDIM + (n - 256)] = f2bf(v);
        } else {
          int cv = n - 512, bb = m >> 12, nt = m & 4095;
          VT[((size_t)bb * CDIM + cv) * NTOK + nt] = f2bf(v);
        }
      }
    }
  }
}

// ---------------------------------------------------------------------------
// Fused attention, TWO-PASS exact softmax, 64-ROW Q-TILE / 512 THREADS.
// R5's proven staged structure scaled 2x: K/V tiles staged once per block,
// shared by 64 q-rows -> L2 traffic per CU HALVED (the R1/R5/R6-invariant
// bottleneck). 8 waves: pass 1 = 4 key-quarters x 2 q-halves; pass 2 =
// 4 producers (2 key-halves x 2 q-halves, S+P) + 4 consumers (4 channel-
// quarters, PV with K=32 contraction: 16 MFMAs/tile each). Full
// __syncthreads per iteration (R5==R6 proved drains are free when staging
// runs 1-2 tiles ahead). Math identical to R5/R6 (verified).
// ---------------------------------------------------------------------------

#define P1_STEP(KF)                                                            \
  {                                                                            \
    f32x4 s0 = (f32x4){0.f, 0.f, 0.f, 0.f};                                    \
    f32x4 s1 = (f32x4){0.f, 0.f, 0.f, 0.f};                                    \
    _Pragma("unroll")                                                          \
    for (int kk = 0; kk < 8; ++kk) {                                           \
      s0 = __builtin_amdgcn_mfma_f32_16x16x32_bf16(aq[0][kk], KF[kk], s0, 0, 0, 0); \
      s1 = __builtin_amdgcn_mfma_f32_16x16x32_bf16(aq[1][kk], KF[kk], s1, 0, 0, 0); \
    }                                                                          \
    float mn0[4], mn1[4];                                                      \
    bool chg = false;                                                          \
    _Pragma("unroll")                                                          \
    for (int r = 0; r < 4; ++r) {                                              \
      mn0[r] = fmaxf(ml[0][r], s0[r]);                                         \
      mn1[r] = fmaxf(ml[1][r], s1[r]);                                         \
      chg = chg || (mn0[r] > ml[0][r]) || (mn1[r] > ml[1][r]);                 \
    }                                                                          \
    if (__any(chg)) {                                                          \
      _Pragma("unroll")                                                        \
      for (int r = 0; r < 4; ++r) {                                            \
        ll[0][r] = ll[0][r] * fexp2(ml[0][r] - mn0[r]) + fexp2(s0[r] - mn0[r]);\
        ml[0][r] = mn0[r];                                                     \
        ll[1][r] = ll[1][r] * fexp2(ml[1][r] - mn1[r]) + fexp2(s1[r] - mn1[r]);\
        ml[1][r] = mn1[r];                                                     \
      }                                                                        \
    } else {                                                                   \
      _Pragma("unroll")                                                        \
      for (int r = 0; r < 4; ++r) {                                            \
        ll[0][r] += fexp2(s0[r] - ml[0][r]);                                   \
        ll[1][r] += fexp2(s1[r] - ml[1][r]);                                   \
      }                                                                        \
    }                                                                          \
  }

#define S_COMPUTE(BK_)                                                         \
  {                                                                            \
    s0 = (f32x4){0.f, 0.f, 0.f, 0.f};                                          \
    s1 = (f32x4){0.f, 0.f, 0.f, 0.f};                                          \
    _Pragma("unroll")                                                          \
    for (int kk = 0; kk < 8; ++kk) {                                           \
      s0 = __builtin_amdgcn_mfma_f32_16x16x32_bf16(aq[0][kk], BK_[kk], s0, 0, 0, 0); \
      s1 = __builtin_amdgcn_mfma_f32_16x16x32_bf16(aq[1][kk], BK_[kk], s1, 0, 0, 0); \
    }                                                                          \
  }

// Combined P -> buffer [64 q][40] u16; this producer's rows qh*32+{0,16}+...,
// cols kh*16+col.
#define P2_WRITE(PN)                                                           \
  {                                                                            \
    _Pragma("unroll")                                                          \
    for (int r = 0; r < 4; ++r) {                                              \
      float sv0 = s0[r];                                                       \
      float rl0 = sv0 > 0.f ? sv0 * sv0 : 0.f;                                 \
      float p0v = c1[0][r] * fexp2(sv0 - mf[0][r]) + a2p * rl0;                \
      (PN)[(qh * 32 + quad * 4 + r) * 40 + kh * 16 + col] = f2bf(p0v);         \
      float sv1 = s1[r];                                                       \
      float rl1 = sv1 > 0.f ? sv1 * sv1 : 0.f;                                 \
      float p1v = c1[1][r] * fexp2(sv1 - mf[1][r]) + a2p * rl1;                \
      (PN)[(qh * 32 + 16 + quad * 4 + r) * 40 + kh * 16 + col] = f2bf(p1v);    \
    }                                                                          \
  }

__global__ __launch_bounds__(512, 2) void fa_kernel(const u16* __restrict__ Qg,
                                                    const u16* __restrict__ Kg,
                                                    const u16* __restrict__ Vtg,
                                                    const u16* __restrict__ xng,
                                                    const float* __restrict__ w1p,
                                                    const float* __restrict__ w2p,
                                                    float* __restrict__ outg) {
  // Layout (bytes): pass1 K [64][256]x2 @0/@32768 (64KB total).
  //   pass2: k2a@0 k2b@16384 (16KB each), v2a@32768 v2b@49152 (16KB each).
  //   pb0@65536 pb1@70656 ([64][40] u16 = 5120 each). mbuf@75776 lbuf@76800.
  //   Epilogue otile [256][68] f32 (69632 B) overlays @0.
  __shared__ __align__(16) char smem[77824];
  float* otile = (float*)smem;
  u16* pb0 = (u16*)(smem + 65536);
  u16* pb1 = (u16*)(smem + 70656);
  float* mbuf = (float*)(smem + 75776);   // [2 qh][4 kq][32 q]
  float* lbuf = (float*)(smem + 76800);

  int b  = blockIdx.x & 3;               // XCD swizzle: same XCD -> same batch
  int q0 = (blockIdx.x >> 2) * 64;

  const u16* Q  = Qg  + (size_t)b * NTOK * CDIM;
  const u16* K  = Kg  + (size_t)b * NTOK * CDIM;
  const u16* Vt = Vtg + (size_t)b * NTOK * CDIM;

  int tid  = threadIdx.x;
  int lane = tid & 63;
  int w    = tid >> 6;
  int col = lane & 15, quad = lane >> 4;

  int qh = w >> 2;                 // q-half (rows qh*32 .. +32), both passes
  int kq = w & 3;                  // pass-1 key quarter
  bool isProd = (w & 2) == 0;      // pass-2 producers: waves 0,1,4,5
  int kh = w & 1;                  // producer key half
  int c4 = (w & 1) + 2 * (w >> 2); // consumer channel quarter (waves 2,3,6,7)

  float e1 = __expf(w1p[0]), e2 = __expf(w2p[0]);
  float a1 = e1 / (e1 + e2), a2 = e2 / (e1 + e2);
  float a2p = a2 * 0.4804530139182014f;  // a2 * ln2^2 (S in exp2 domain)

  // ---- Q A-frags for this wave's q-half (2 groups), live both passes ----
  bf16x8 aq[2][8];
#pragma unroll
  for (int g = 0; g < 2; ++g)
#pragma unroll
    for (int kk = 0; kk < 8; ++kk)
      aq[g][kk] = *(const bf16x8*)&Q[(size_t)(q0 + qh * 32 + g * 16 + col) * CDIM +
                                     kk * 32 + quad * 8];

  // ---- staging offsets (512 threads cooperate; u16 elements) ----
  // pass1 K [64][256]: 4 instrs; row = it*16 + (t>>5); chunk = (t&31)^row.
  int koff1[4];
#pragma unroll
  for (int it = 0; it < 4; ++it) {
    int row = it * 16 + (tid >> 5);
    int ch  = (tid & 31) ^ (row & 31);
    koff1[it] = row * CDIM + ch * 8;
  }
  // pass2 K [32][256]: 2 instrs; same formula, rows 0..31.
  int koff2[2];
#pragma unroll
  for (int it = 0; it < 2; ++it) {
    int row = it * 16 + (tid >> 5);
    int ch  = (tid & 31) ^ row;
    koff2[it] = row * CDIM + ch * 8;
  }
  // pass2 V [256][32]: 2 instrs; vr = it*128 + (t>>2); slot = t&3 holds
  // chunk g3 = slot ^ ((vr>>1)&3).
  int voff2[2];
#pragma unroll
  for (int it = 0; it < 2; ++it) {
    int vr = it * 128 + (tid >> 2);
    int g3 = (tid & 3) ^ ((vr >> 1) & 3);
    voff2[it] = vr * NTOK + g3 * 8;
  }

  auto stage1 = [&](int n1, u16* dst) {
    const u16* kgb = K + (size_t)n1 * CDIM;
#pragma unroll
    for (int it = 0; it < 4; ++it)
      gload_lds16(kgb + koff1[it], dst + it * 4096 + (tid >> 6) * 512 + lane * 8);
  };
  auto stageK2 = [&](int n1, u16* dst) {
    const u16* kgb = K + (size_t)n1 * CDIM;
#pragma unroll
    for (int it = 0; it < 2; ++it)
      gload_lds16(kgb + koff2[it], dst + it * 4096 + (tid >> 6) * 512 + lane * 8);
  };
  auto stageV2 = [&](int n1, u16* dst) {
    const u16* vgb = Vt + n1;
#pragma unroll
    for (int it = 0; it < 2; ++it)
      gload_lds16(vgb + voff2[it], dst + it * 4096 + (tid >> 6) * 512 + lane * 8);
  };

  // =========================== PASS 1: m, l ================================
  u16* ka = (u16*)smem;            // [64][256] u16 = 32 KB
  u16* kb = ka + 16384;

  stage1(0, ka);

  float ml[2][4], ll[2][4];
#pragma unroll
  for (int g = 0; g < 2; ++g)
#pragma unroll
    for (int r = 0; r < 4; ++r) { ml[g][r] = -3e38f; ll[g][r] = 0.f; }

  __syncthreads();

  int kr1 = kq * 16 + col;   // this wave's keys within the 64-key tile
  for (int t = 0; t < 64; ++t) {
    if (t < 63) stage1((t + 1) * 64, kb);

    bf16x8 bkf[8];
#pragma unroll
    for (int kk = 0; kk < 8; ++kk)
      bkf[kk] = *(const bf16x8*)&ka[(size_t)kr1 * 256 + (((kk * 4 + quad) ^ kr1) & 31) * 8];
    P1_STEP(bkf)

    __syncthreads();
    u16* tk = ka; ka = kb; kb = tk;
  }

  // merge across the 16 cols of this wave (keys within quarter)
#pragma unroll
  for (int off = 1; off < 16; off <<= 1)
#pragma unroll
    for (int g = 0; g < 2; ++g)
#pragma unroll
      for (int r = 0; r < 4; ++r) {
        float mo = __shfl_xor(ml[g][r], off);
        float lo = __shfl_xor(ll[g][r], off);
        float mn = fmaxf(ml[g][r], mo);
        ll[g][r] = ll[g][r] * fexp2(ml[g][r] - mn) + lo * fexp2(mo - mn);
        ml[g][r] = mn;
      }
  // merge across the 4 key-quarter waves of this q-half via LDS, once
  if (col == 0) {
#pragma unroll
    for (int g = 0; g < 2; ++g)
#pragma unroll
      for (int r = 0; r < 4; ++r) {
        int qr = g * 16 + quad * 4 + r;
        mbuf[qh * 128 + kq * 32 + qr] = ml[g][r];
        lbuf[qh * 128 + kq * 32 + qr] = ll[g][r];
      }
  }
  __syncthreads();
  float mf[2][4], c1[2][4];
#pragma unroll
  for (int g = 0; g < 2; ++g)
#pragma unroll
    for (int r = 0; r < 4; ++r) {
      int qr = g * 16 + quad * 4 + r;
      float M = -3e38f, L = 0.f;
#pragma unroll
      for (int k2 = 0; k2 < 4; ++k2) {
        float mo = mbuf[qh * 128 + k2 * 32 + qr];
        float lo = lbuf[qh * 128 + k2 * 32 + qr];
        float mn = fmaxf(M, mo);
        L = L * fexp2(M - mn) + lo * fexp2(mo - mn);
        M = mn;
      }
      mf[g][r] = M;
      c1[g][r] = a1 / L;
    }
  __syncthreads();   // mbuf reads done before pass-2 staging reuses LDS

  // =========================== PASS 2: P, O ================================
  u16* k2a = (u16*)smem;                 // [32][256] u16 = 16 KB
  u16* k2b = k2a + 8192;
  u16* v2a = (u16*)(smem + 32768);       // [256][32] u16 = 16 KB
  u16* v2b = v2a + 8192;

  f32x4 o[4][4];                         // consumer: [q-group][ch-subtile]
#pragma unroll
  for (int i = 0; i < 4; ++i)
#pragma unroll
    for (int j = 0; j < 4; ++j) o[i][j] = (f32x4){0.f, 0.f, 0.f, 0.f};

  int kr2 = kh * 16 + col;   // producer keys within 32-key tile

  // prologue: K(0); sync; S(0)->P(0); K(1),V(0); sync
  stageK2(0, k2a);
  __syncthreads();
  if (isProd) {
    bf16x8 bk[8];
#pragma unroll
    for (int kk = 0; kk < 8; ++kk)
      bk[kk] = *(const bf16x8*)&k2a[(size_t)kr2 * 256 + (((kk * 4 + quad) ^ kr2) & 31) * 8];
    f32x4 s0, s1;
    S_COMPUTE(bk)
    P2_WRITE(pb0)
  }
  stageK2(32, k2b);
  stageV2(0, v2a);
  __syncthreads();

  for (int t = 0; t < 128; ++t) {
    if (t < 126) stageK2((t + 2) * 32, (t & 1) ? k2b : k2a);
    if (t < 127) stageV2((t + 1) * 32, ((t + 1) & 1) ? v2b : v2a);

    if (isProd) {
      // producer: S(t+1) from K(t+1), P(t+1) -> pb[(t+1)&1]
      if (t < 127) {
        const u16* ksrc = ((t + 1) & 1) ? k2b : k2a;
        bf16x8 bk[8];
#pragma unroll
        for (int kk = 0; kk < 8; ++kk)
          bk[kk] = *(const bf16x8*)&ksrc[(size_t)kr2 * 256 + (((kk * 4 + quad) ^ kr2) & 31) * 8];
        f32x4 s0, s1;
        __builtin_amdgcn_s_setprio(1);
        S_COMPUTE(bk)
        __builtin_amdgcn_s_setprio(0);
        P2_WRITE(((t + 1) & 1) ? pb1 : pb0)
      }
    } else {
      // consumer: PV(t) from P(t), V(t): 4 q-groups x 4 ch-subtiles, K=32
      const u16* psrc = (t & 1) ? pb1 : pb0;
      const u16* vsrc = (t & 1) ? v2b : v2a;
      bf16x8 pa[4];
#pragma unroll
      for (int i = 0; i < 4; ++i)
        pa[i] = *(const bf16x8*)&psrc[(size_t)(i * 16 + col) * 40 + quad * 8];
      bf16x8 bv[4];
#pragma unroll
      for (int j = 0; j < 4; ++j) {
        int vr = c4 * 64 + j * 16 + col;
        bv[j] = *(const bf16x8*)&vsrc[(size_t)vr * 32 + ((quad ^ ((vr >> 1) & 3)) & 3) * 8];
      }
      __builtin_amdgcn_s_setprio(1);
#pragma unroll
      for (int i = 0; i < 4; ++i)
#pragma unroll
        for (int j = 0; j < 4; ++j)
          o[i][j] = __builtin_amdgcn_mfma_f32_16x16x32_bf16(pa[i], bv[j], o[i][j], 0, 0, 0);
      __builtin_amdgcn_s_setprio(0);
    }
    __syncthreads();   // staging landed (own-wave vmcnt drained) + P handoff
  }

  // ---- epilogue: residual + transpose to [c][n] (consumers hold O) ----
  if (!isProd) {
#pragma unroll
    for (int i = 0; i < 4; ++i)
#pragma unroll
      for (int j = 0; j < 4; ++j) {
        int c = c4 * 64 + j * 16 + col;
        float4 v4;
        float* vv = (float*)&v4;
#pragma unroll
        for (int r = 0; r < 4; ++r) {
          int row = i * 16 + quad * 4 + r;
          vv[r] = o[i][j][r] + bf2f(xng[((size_t)b * NTOK + q0 + row) * CDIM + c]);
        }
        *(float4*)&otile[(size_t)c * 68 + i * 16 + quad * 4] = v4;
      }
  }
  __syncthreads();

#pragma unroll
  for (int it = 0; it < 8; ++it) {
    int c  = it * 32 + (tid >> 4);
    int n4 = tid & 15;
    *(float4*)&outg[((size_t)b * CDIM + c) * NTOK + q0 + n4 * 4] =
        *(const float4*)&otile[(size_t)c * 68 + n4 * 4];
  }
}

// ---------------------------------------------------------------------------
extern "C" void kernel_launch(void* const* d_in, const int* in_sizes, int n_in,
                              void* d_out, int out_size, void* d_ws, size_t ws_size,
                              hipStream_t stream) {
  const float* x     = (const float*)d_in[0];
  const float* gamma = (const float*)d_in[1];
  const float* beta  = (const float*)d_in[2];
  const float* Wq    = (const float*)d_in[3];
  const float* Wk    = (const float*)d_in[4];
  const float* Wv    = (const float*)d_in[5];
  const float* w1    = (const float*)d_in[6];
  const float* w2    = (const float*)d_in[7];
  float* out = (float*)d_out;

  char* ws = (char*)d_ws;
  size_t off = 0;
  u16* xn  = (u16*)(ws + off); off += (size_t)BATCH * NTOK * CDIM * 2;
  u16* WT3 = (u16*)(ws + off); off += (size_t)3 * CDIM * CDIM * 2;   // [768][256]
  u16* Qb  = (u16*)(ws + off); off += (size_t)BATCH * NTOK * CDIM * 2;
  u16* Kb  = (u16*)(ws + off); off += (size_t)BATCH * NTOK * CDIM * 2;
  u16* VT  = (u16*)(ws + off); off += (size_t)BATCH * NTOK * CDIM * 2;  // [b][c][n]

  const float LOG2E = 1.4426950408889634f;

  // 1) LayerNorm -> xn bf16 [B*N, C]
  ln_kernel<<<dim3(BATCH * (NTOK / 32)), 256, 0, stream>>>(x, gamma, beta, xn);

  // 2) stacked transposed weights (Wq pre-scaled by log2e -> exp2-domain S)
  wt_kernel<<<dim3(8, 8), dim3(32, 8), 0, stream>>>(Wq, WT3, LOG2E);
  wt_kernel<<<dim3(8, 8), dim3(32, 8), 0, stream>>>(Wk, WT3 + 256 * 256, 1.0f);
  wt_kernel<<<dim3(8, 8), dim3(32, 8), 0, stream>>>(Wv, WT3 + 512 * 256, 1.0f);

  // 3) fused Q/K/V projection (one launch)
  qkv_kernel<<<dim3(12, 128), 256, 0, stream>>>(xn, WT3, Qb, Kb, VT);

  // 4) fused attention (two-pass, 64-row Q-tile, halved L2 traffic)
  fa_kernel<<<dim3(256), 512, 0, stream>>>(Qb, Kb, VT, xn, w1, w2, out);
}